// Round 1
// baseline (490.644 us; speedup 1.0000x reference)
//
#include <hip/hip_runtime.h>

// SSD MultiBoxLoss for B=64, P=29126, G=24, 2 classes, scalar fp32 output.
static constexpr int B_ = 64;
static constexpr int P_ = 29126;
static constexpr int G_ = 24;
static constexpr float THRESH_ = 0.35f;
static constexpr int NEGPOS_ = 7;

// ---------------------------------------------------------------- kernel 1
// best_prior_idx[b,g] = argmax_p IoU(gt[b,g], prior[p])  (first occurrence)
__global__ void k_best_prior(const float* __restrict__ gt,
                             const float* __restrict__ priors,
                             int* __restrict__ bpi)
{
    const int bg = blockIdx.x;            // 0 .. B*G-1
    const int b = bg / G_, g = bg % G_;
    const float tx0 = gt[(b*G_+g)*4+0];
    const float ty0 = gt[(b*G_+g)*4+1];
    const float tx1 = gt[(b*G_+g)*4+2];
    const float ty1 = gt[(b*G_+g)*4+3];
    const float area_t = (tx1-tx0)*(ty1-ty0);

    float bestv = -1.0f; int bestp = 0;
    for (int p = threadIdx.x; p < P_; p += blockDim.x) {
        const float cx = priors[p*4+0], cy = priors[p*4+1];
        const float w  = priors[p*4+2], h  = priors[p*4+3];
        const float px0 = cx - w*0.5f, py0 = cy - h*0.5f;
        const float px1 = cx + w*0.5f, py1 = cy + h*0.5f;
        const float lx = fmaxf(tx0, px0), ly = fmaxf(ty0, py0);
        const float rx = fminf(tx1, px1), ry = fminf(ty1, py1);
        const float iw = fmaxf(rx-lx, 0.0f), ih = fmaxf(ry-ly, 0.0f);
        const float inter = iw*ih;
        const float area_p = (px1-px0)*(py1-py0);
        const float iou = inter / ((area_t + area_p) - inter);
        if (iou > bestv) { bestv = iou; bestp = p; }   // strict > => first idx
    }
    __shared__ float sv[256];
    __shared__ int   si[256];
    sv[threadIdx.x] = bestv; si[threadIdx.x] = bestp;
    __syncthreads();
    for (int off = 128; off > 0; off >>= 1) {
        if ((int)threadIdx.x < off) {
            const float v2 = sv[threadIdx.x+off];
            const int   i2 = si[threadIdx.x+off];
            if (v2 > sv[threadIdx.x] ||
                (v2 == sv[threadIdx.x] && i2 < si[threadIdx.x])) {
                sv[threadIdx.x] = v2; si[threadIdx.x] = i2;
            }
        }
        __syncthreads();
    }
    if (threadIdx.x == 0) bpi[bg] = si[0];
}

// ---------------------------------------------------------------- kernel 2
// per (b,p): bto = max_g IoU, bti = argmax_g IoU (first occurrence)
__global__ void k_match(const float* __restrict__ gt,
                        const float* __restrict__ priors,
                        float* __restrict__ bto, int* __restrict__ bti)
{
    const int b = blockIdx.y;
    const int p = blockIdx.x*blockDim.x + threadIdx.x;
    __shared__ float sgt[G_*4];
    if (threadIdx.x < G_*4) sgt[threadIdx.x] = gt[b*G_*4 + threadIdx.x];
    __syncthreads();
    if (p >= P_) return;

    const float cx = priors[p*4+0], cy = priors[p*4+1];
    const float w  = priors[p*4+2], h  = priors[p*4+3];
    const float px0 = cx - w*0.5f, py0 = cy - h*0.5f;
    const float px1 = cx + w*0.5f, py1 = cy + h*0.5f;
    const float area_p = (px1-px0)*(py1-py0);

    float bestv = -1.0f; int bestg = 0;
    for (int g = 0; g < G_; ++g) {
        const float tx0 = sgt[g*4+0], ty0 = sgt[g*4+1];
        const float tx1 = sgt[g*4+2], ty1 = sgt[g*4+3];
        const float area_t = (tx1-tx0)*(ty1-ty0);
        const float lx = fmaxf(tx0, px0), ly = fmaxf(ty0, py0);
        const float rx = fminf(tx1, px1), ry = fminf(ty1, py1);
        const float iw = fmaxf(rx-lx, 0.0f), ih = fmaxf(ry-ly, 0.0f);
        const float inter = iw*ih;
        const float iou = inter / ((area_t + area_p) - inter);
        if (iou > bestv) { bestv = iou; bestg = g; }   // strict > => first idx
    }
    bto[b*P_+p] = bestv;
    bti[b*P_+p] = bestg;
}

// ---------------------------------------------------------------- kernel 3
// sequential per-batch overrides (last-wins for duplicate best priors)
__global__ void k_override(const int* __restrict__ bpi,
                           float* __restrict__ bto, int* __restrict__ bti)
{
    const int b = blockIdx.x*blockDim.x + threadIdx.x;
    if (b >= B_) return;
    for (int g = 0; g < G_; ++g) {
        const int p = bpi[b*G_+g];
        bto[b*P_+p] = 2.0f;
        bti[b*P_+p] = g;
    }
}

// ---------------------------------------------------------------- kernel 4
// per (b,p): loc smooth-L1 (pos), CE, mine; accumulate sums.
// mine is written OVER bto (read-then-write same element).
__global__ void k_loss(const float* __restrict__ loc,
                       const float* __restrict__ conf,
                       const float* __restrict__ gt,
                       const int* __restrict__ labels,
                       const float* __restrict__ priors,
                       float* __restrict__ bto_mine,
                       const int* __restrict__ bti,
                       int* __restrict__ num_pos,
                       float* __restrict__ accs,        // [0]=lossL [1]=posCE [2]=topkC
                       unsigned int* __restrict__ totalPos)
{
    const int b = blockIdx.y;
    const int p = blockIdx.x*blockDim.x + threadIdx.x;
    float lL = 0.0f, pce = 0.0f; int isPos = 0;
    if (p < P_) {
        const int idx = b*P_ + p;
        const float overlap = bto_mine[idx];
        const int g = bti[idx];
        const int lab = labels[b*G_+g];
        const int c = (overlap < THRESH_) ? 0 : lab;

        const float x0 = conf[idx*2+0], x1 = conf[idx*2+1];
        const float mx = fmaxf(x0, x1);
        const float lse = mx + logf(expf(x0-mx) + expf(x1-mx));
        const float gold = (c == 0) ? x0 : x1;
        const float ce = lse - gold;

        float mine;
        if (c > 0) {
            isPos = 1; pce = ce; mine = 0.0f;
            const float tx0 = gt[(b*G_+g)*4+0], ty0 = gt[(b*G_+g)*4+1];
            const float tx1 = gt[(b*G_+g)*4+2], ty1 = gt[(b*G_+g)*4+3];
            const float cx = priors[p*4+0], cy = priors[p*4+1];
            const float w  = priors[p*4+2], h  = priors[p*4+3];
            const float gcx = ((tx0+tx1)*0.5f - cx) / (0.1f*w);
            const float gcy = ((ty0+ty1)*0.5f - cy) / (0.1f*h);
            const float gw  = logf((tx1-tx0)/w) / 0.2f;
            const float gh  = logf((ty1-ty0)/h) / 0.2f;
            const float d0 = fabsf(loc[idx*4+0] - gcx);
            const float d1 = fabsf(loc[idx*4+1] - gcy);
            const float d2 = fabsf(loc[idx*4+2] - gw);
            const float d3 = fabsf(loc[idx*4+3] - gh);
            lL  = (d0 < 1.0f) ? 0.5f*d0*d0 : d0-0.5f;
            lL += (d1 < 1.0f) ? 0.5f*d1*d1 : d1-0.5f;
            lL += (d2 < 1.0f) ? 0.5f*d2*d2 : d2-0.5f;
            lL += (d3 < 1.0f) ? 0.5f*d3*d3 : d3-0.5f;
        } else {
            mine = ce;
        }
        bto_mine[idx] = mine;
    }
    __shared__ float sL[256], sC[256];
    __shared__ int   sP[256];
    sL[threadIdx.x] = lL; sC[threadIdx.x] = pce; sP[threadIdx.x] = isPos;
    __syncthreads();
    for (int off = 128; off > 0; off >>= 1) {
        if ((int)threadIdx.x < off) {
            sL[threadIdx.x] += sL[threadIdx.x+off];
            sC[threadIdx.x] += sC[threadIdx.x+off];
            sP[threadIdx.x] += sP[threadIdx.x+off];
        }
        __syncthreads();
    }
    if (threadIdx.x == 0) {
        atomicAdd(&accs[0], sL[0]);
        atomicAdd(&accs[1], sC[0]);
        atomicAdd(&num_pos[b], sP[0]);
        atomicAdd(totalPos, (unsigned int)sP[0]);
    }
}

// ---------------------------------------------------------------- kernel 5
// per batch: sum of top-k values of mine (k = min(7*num_pos, P-1))
// 4-pass radix select over uint view (all mine >= 0 so bits are monotone).
__global__ void k_topk(const float* __restrict__ mine,
                       const int* __restrict__ num_pos,
                       float* __restrict__ accs)
{
    const int b = blockIdx.x;
    const int np = num_pos[b];
    long long kll = (long long)NEGPOS_ * (long long)np;
    if (kll > (long long)(P_-1)) kll = P_-1;
    const int k = (int)kll;
    if (k <= 0) return;                               // uniform: whole block exits

    const float* row = mine + (size_t)b * P_;
    __shared__ unsigned int hist[256];
    __shared__ unsigned int sh_prefix;
    __shared__ int sh_kk;

    unsigned int prefix = 0; int kk = k;
    for (int pass = 3; pass >= 0; --pass) {
        if (threadIdx.x < 256) hist[threadIdx.x] = 0;
        __syncthreads();
        const unsigned int highmask =
            (pass == 3) ? 0u : (0xFFFFFFFFu << ((pass+1)*8));
        for (int p = threadIdx.x; p < P_; p += blockDim.x) {
            const unsigned int u = __float_as_uint(row[p]);
            if ((u & highmask) == (prefix & highmask))
                atomicAdd(&hist[(u >> (pass*8)) & 0xFFu], 1u);
        }
        __syncthreads();
        if (threadIdx.x == 0) {
            unsigned int cum = 0; int bin = 255;
            for (; bin > 0; --bin) {
                cum += hist[bin];
                if ((int)cum >= kk) break;
            }
            if ((int)cum < kk) cum += hist[0];        // bin==0 fallthrough
            sh_prefix = prefix | ((unsigned int)bin << (pass*8));
            sh_kk = kk - (int)(cum - hist[bin]);
        }
        __syncthreads();
        prefix = sh_prefix; kk = sh_kk;
        __syncthreads();
    }

    const float T = __uint_as_float(prefix);
    float sum = 0.0f; int cnt = 0;
    for (int p = threadIdx.x; p < P_; p += blockDim.x) {
        const float v = row[p];
        if (v > T) { sum += v; ++cnt; }
    }
    __shared__ float ss[256];
    __shared__ int   sc[256];
    ss[threadIdx.x] = sum; sc[threadIdx.x] = cnt;
    __syncthreads();
    for (int off = 128; off > 0; off >>= 1) {
        if ((int)threadIdx.x < off) {
            ss[threadIdx.x] += ss[threadIdx.x+off];
            sc[threadIdx.x] += sc[threadIdx.x+off];
        }
        __syncthreads();
    }
    if (threadIdx.x == 0) {
        const float add = ss[0] + (float)(k - sc[0]) * T;
        atomicAdd(&accs[2], add);
    }
}

// ---------------------------------------------------------------- kernel 6
__global__ void k_final(const float* __restrict__ accs,
                        const unsigned int* __restrict__ totalPos,
                        float* __restrict__ out)
{
    const float N = fmaxf((float)(*totalPos), 1.0f);
    out[0] = (2.0f*accs[0] + accs[1] + accs[2]) / N;
}

// ----------------------------------------------------------------
extern "C" void kernel_launch(void* const* d_in, const int* in_sizes, int n_in,
                              void* d_out, int out_size, void* d_ws, size_t ws_size,
                              hipStream_t stream)
{
    const float* loc    = (const float*)d_in[0];   // [B,P,4]
    const float* conf   = (const float*)d_in[1];   // [B,P,2]
    const float* gt     = (const float*)d_in[2];   // [B,G,4]
    const int*   labels = (const int*)d_in[3];     // [B,G]
    const float* priors = (const float*)d_in[4];   // [P,4]
    float* out = (float*)d_out;

    char* ws = (char*)d_ws;
    float* bto     = (float*)ws;                               // B*P floats (reused as mine)
    int*   bti     = (int*)(ws + (size_t)B_*P_*4);             // B*P ints
    int*   bpi     = (int*)(ws + (size_t)2*B_*P_*4);           // B*G ints
    int*   num_pos = (int*)(ws + (size_t)2*B_*P_*4 + B_*G_*4); // B ints
    float* accs    = (float*)((char*)num_pos + B_*4);          // 3 floats
    unsigned int* totalPos = (unsigned int*)((char*)accs + 3*4);

    // zero the small accumulator region (num_pos + accs + totalPos)
    hipMemsetAsync(num_pos, 0, (size_t)B_*4 + 4*4, stream);

    const int pb = (P_ + 255) / 256;
    k_best_prior<<<dim3(B_*G_), dim3(256), 0, stream>>>(gt, priors, bpi);
    k_match<<<dim3(pb, B_), dim3(256), 0, stream>>>(gt, priors, bto, bti);
    k_override<<<dim3(1), dim3(64), 0, stream>>>(bpi, bto, bti);
    k_loss<<<dim3(pb, B_), dim3(256), 0, stream>>>(loc, conf, gt, labels, priors,
                                                   bto, bti, num_pos, accs, totalPos);
    k_topk<<<dim3(B_), dim3(256), 0, stream>>>(bto, num_pos, accs);
    k_final<<<dim3(1), dim3(1), 0, stream>>>(accs, totalPos, out);
}

// Round 2
// 125.261 us; speedup vs baseline: 3.9170x; 3.9170x over previous
//
#include <hip/hip_runtime.h>

// SSD MultiBoxLoss: B=64, P=29126, G=24, 2 classes, scalar fp32 output.
static constexpr int B_ = 64;
static constexpr int P_ = 29126;
static constexpr int G_ = 24;
static constexpr float THRESH_ = 0.35f;
static constexpr int NEGPOS_ = 7;
static constexpr int CH_ = 15;            // ceil(P/2048) chunks of 8*256 priors
static constexpr int NBLK_ = CH_ * B_;    // 960 partial slots

__device__ inline unsigned long long shflxor64(unsigned long long v, int m) {
    unsigned int lo = (unsigned int)(v & 0xFFFFFFFFull);
    unsigned int hi = (unsigned int)(v >> 32);
    lo = __shfl_xor(lo, m, 64);
    hi = __shfl_xor(hi, m, 64);
    return ((unsigned long long)hi << 32) | lo;
}

// ---------------------------------------------------------------- kernel 1
// Per (b,p): bto = max_g IoU, bti = argmax_g IoU (first occurrence).
// Fused: per-(b,g) best prior via packed atomicMax:
//   pk = (iou_bits << 32) | (0xFFFFFFFF - p)   (max => best iou, tie => min p)
__global__ __launch_bounds__(256) void k_match(
    const float4* __restrict__ gt4,      // [B*G]
    const float4* __restrict__ priors4,  // [P]  (cx,cy,w,h)
    float* __restrict__ bto, int* __restrict__ bti,
    unsigned long long* __restrict__ bp_pack)   // [B*G], zeroed
{
    const int b = blockIdx.y;
    const int tid = threadIdx.x;
    __shared__ float4 sgt[G_];
    __shared__ float  sarea[G_];
    __shared__ unsigned long long swv[4][G_];
    if (tid < G_) {
        const float4 t = gt4[b*G_ + tid];
        sgt[tid] = t;
        sarea[tid] = (t.z - t.x) * (t.w - t.y);
    }
    __syncthreads();

    unsigned long long best[G_];
#pragma unroll
    for (int g = 0; g < G_; ++g) best[g] = 0ull;

#pragma unroll
    for (int c = 0; c < 8; ++c) {
        const int p = blockIdx.x*2048 + c*256 + tid;
        if (p < P_) {
            const float4 pr = priors4[p];
            const float px0 = pr.x - pr.z*0.5f, py0 = pr.y - pr.w*0.5f;
            const float px1 = pr.x + pr.z*0.5f, py1 = pr.y + pr.w*0.5f;
            const float area_p = (px1-px0)*(py1-py0);
            float bv = -1.0f; int bg = 0;
#pragma unroll
            for (int g = 0; g < G_; ++g) {
                const float4 t = sgt[g];
                const float lx = fmaxf(t.x, px0), ly = fmaxf(t.y, py0);
                const float rx = fminf(t.z, px1), ry = fminf(t.w, py1);
                const float iw = fmaxf(rx-lx, 0.0f), ih = fmaxf(ry-ly, 0.0f);
                const float inter = iw*ih;
                const float iou = inter / ((sarea[g] + area_p) - inter);
                if (iou > bv) { bv = iou; bg = g; }   // strict > => first g
                const unsigned long long pk =
                    ((unsigned long long)__float_as_uint(iou) << 32)
                    | (unsigned long long)(0xFFFFFFFFu - (unsigned int)p);
                if (pk > best[g]) best[g] = pk;
            }
            bto[b*P_ + p] = bv;
            bti[b*P_ + p] = bg;
        }
    }

    const int lane = tid & 63, wave = tid >> 6;
#pragma unroll
    for (int g = 0; g < G_; ++g) {
        unsigned long long v = best[g];
        for (int m = 32; m; m >>= 1) {
            const unsigned long long o = shflxor64(v, m);
            if (o > v) v = o;
        }
        if (lane == 0) swv[wave][g] = v;
    }
    __syncthreads();
    if (tid < G_) {
        unsigned long long m = swv[0][tid];
        if (swv[1][tid] > m) m = swv[1][tid];
        if (swv[2][tid] > m) m = swv[2][tid];
        if (swv[3][tid] > m) m = swv[3][tid];
        atomicMax(&bp_pack[b*G_ + tid], m);
    }
}

// ---------------------------------------------------------------- kernel 2
// sequential per-batch overrides (last-g-wins for duplicate best priors)
__global__ void k_override(const unsigned long long* __restrict__ bp_pack,
                           float* __restrict__ bto, int* __restrict__ bti)
{
    const int b = threadIdx.x;     // 64 threads
    if (b >= B_) return;
    for (int g = 0; g < G_; ++g) {
        const unsigned long long pk = bp_pack[b*G_ + g];
        const int p = (int)(0xFFFFFFFFu - (unsigned int)(pk & 0xFFFFFFFFull));
        bto[b*P_ + p] = 2.0f;
        bti[b*P_ + p] = g;
    }
}

// ---------------------------------------------------------------- kernel 3
// per (b,p): loc smooth-L1 (pos), CE, mine (overwrites bto). NO global atomics:
// per-block partials into pl/pc/pp.
__global__ __launch_bounds__(256) void k_loss(
    const float4* __restrict__ loc4,   // [B*P]
    const float2* __restrict__ conf2,  // [B*P]
    const float4* __restrict__ gt4,    // [B*G]
    const int* __restrict__ labels,    // [B*G]
    const float4* __restrict__ priors4,
    float* __restrict__ bto_mine,
    const int* __restrict__ bti,
    float* __restrict__ pl, float* __restrict__ pc, int* __restrict__ pp)
{
    const int b = blockIdx.y;
    const int tid = threadIdx.x;
    float lL = 0.0f, pce = 0.0f; int np = 0;

#pragma unroll
    for (int c = 0; c < 8; ++c) {
        const int p = blockIdx.x*2048 + c*256 + tid;
        if (p < P_) {
            const int idx = b*P_ + p;
            const float overlap = bto_mine[idx];
            const int g = bti[idx];
            const int lab = labels[b*G_ + g];
            const int cc = (overlap < THRESH_) ? 0 : lab;

            const float2 x = conf2[idx];
            const float mx = fmaxf(x.x, x.y);
            const float lse = mx + logf(expf(x.x - mx) + expf(x.y - mx));
            const float ce = lse - ((cc == 0) ? x.x : x.y);

            float mine = ce;
            if (cc > 0) {
                np += 1; pce += ce; mine = 0.0f;
                const float4 t  = gt4[b*G_ + g];
                const float4 pr = priors4[p];
                const float gcx = ((t.x + t.z)*0.5f - pr.x) / (0.1f*pr.z);
                const float gcy = ((t.y + t.w)*0.5f - pr.y) / (0.1f*pr.w);
                const float gw  = logf((t.z - t.x)/pr.z) / 0.2f;
                const float gh  = logf((t.w - t.y)/pr.w) / 0.2f;
                const float4 l = loc4[idx];
                const float d0 = fabsf(l.x - gcx);
                const float d1 = fabsf(l.y - gcy);
                const float d2 = fabsf(l.z - gw);
                const float d3 = fabsf(l.w - gh);
                lL += (d0 < 1.0f) ? 0.5f*d0*d0 : d0 - 0.5f;
                lL += (d1 < 1.0f) ? 0.5f*d1*d1 : d1 - 0.5f;
                lL += (d2 < 1.0f) ? 0.5f*d2*d2 : d2 - 0.5f;
                lL += (d3 < 1.0f) ? 0.5f*d3*d3 : d3 - 0.5f;
            }
            bto_mine[idx] = mine;
        }
    }

    __shared__ float sL[256], sC[256];
    __shared__ int   sP[256];
    sL[tid] = lL; sC[tid] = pce; sP[tid] = np;
    __syncthreads();
    for (int off = 128; off > 0; off >>= 1) {
        if (tid < off) {
            sL[tid] += sL[tid+off];
            sC[tid] += sC[tid+off];
            sP[tid] += sP[tid+off];
        }
        __syncthreads();
    }
    if (tid == 0) {
        const int o = b*CH_ + blockIdx.x;
        pl[o] = sL[0]; pc[o] = sC[0]; pp[o] = sP[0];
    }
}

// ---------------------------------------------------------------- kernel 4
// deterministic reduction of partials: accs[0]=lossL, accs[1]=posCE,
// accs[3]=totalPos(float); num_pos[b]; accs[2]:=0 (unused now).
__global__ __launch_bounds__(256) void k_reduce(
    const float* __restrict__ pl, const float* __restrict__ pc,
    const int* __restrict__ pp,
    int* __restrict__ num_pos, float* __restrict__ accs)
{
    const int tid = threadIdx.x;
    float sL = 0.0f, sC = 0.0f;
    for (int i = tid; i < NBLK_; i += 256) { sL += pl[i]; sC += pc[i]; }
    int tp = 0;
    if (tid < B_) {
        int s = 0;
        for (int j = 0; j < CH_; ++j) s += pp[tid*CH_ + j];
        num_pos[tid] = s; tp = s;
    }
    __shared__ float aL[256], aC[256];
    __shared__ int   aP[256];
    aL[tid] = sL; aC[tid] = sC; aP[tid] = tp;
    __syncthreads();
    for (int off = 128; off > 0; off >>= 1) {
        if (tid < off) {
            aL[tid] += aL[tid+off];
            aC[tid] += aC[tid+off];
            aP[tid] += aP[tid+off];
        }
        __syncthreads();
    }
    if (tid == 0) {
        accs[0] = aL[0]; accs[1] = aC[0]; accs[2] = 0.0f;
        accs[3] = (float)aP[0];
    }
}

// ---------------------------------------------------------------- kernel 5
// per batch: sum of top-k of mine, k = min(7*num_pos, P-1).
// 4-pass radix select (uint view, all mine >= 0). 1024 threads,
// per-wave histograms + parallel suffix scan.
__global__ __launch_bounds__(1024) void k_topk(
    const float* __restrict__ mine, const int* __restrict__ num_pos,
    float* __restrict__ ctop)
{
    const int b = blockIdx.x;
    const int tid = threadIdx.x;
    const int np = num_pos[b];
    int k = NEGPOS_ * np; if (k > P_-1) k = P_-1;
    if (k <= 0) { if (tid == 0) ctop[b] = 0.0f; return; }   // block-uniform

    const float* row = mine + (size_t)b * P_;
    const int wave = tid >> 6;

    __shared__ unsigned int hist[16*256];
    __shared__ unsigned int sc0[256], sc1[256];
    __shared__ unsigned int sh_prefix;
    __shared__ int sh_kk;

    unsigned int prefix = 0; int kk = k;
    for (int pass = 3; pass >= 0; --pass) {
        for (int i = tid; i < 16*256; i += 1024) hist[i] = 0;
        __syncthreads();
        const unsigned int highmask =
            (pass == 3) ? 0u : (0xFFFFFFFFu << ((pass+1)*8));
        for (int p = tid; p < P_; p += 1024) {
            const unsigned int u = __float_as_uint(row[p]);
            if ((u & highmask) == (prefix & highmask))
                atomicAdd(&hist[wave*256 + ((u >> (pass*8)) & 255u)], 1u);
        }
        __syncthreads();
        if (tid < 256) {
            unsigned int m = 0;
#pragma unroll
            for (int w = 0; w < 16; ++w) m += hist[w*256 + (255 - tid)];
            sc0[tid] = m;                       // sc0[r] = count(bin = 255-r)
        }
        __syncthreads();
        // inclusive scan over r (Hillis-Steele ping-pong, 8 steps)
        unsigned int* src = sc0; unsigned int* dst = sc1;
        for (int off = 1; off < 256; off <<= 1) {
            if (tid < 256) {
                unsigned int v = src[tid];
                if (tid >= off) v += src[tid - off];
                dst[tid] = v;
            }
            __syncthreads();
            unsigned int* t = src; src = dst; dst = t;
        }
        // src[r] = count of elements with bin >= 255-r
        if (tid < 256) {
            const int bin = 255 - tid;
            const int cum = (int)src[tid];
            const int cumNext = (tid == 0) ? 0 : (int)src[tid-1];  // bins > bin
            if (cum >= kk && cumNext < kk) {     // exactly one thread
                sh_prefix = prefix | ((unsigned int)bin << (pass*8));
                sh_kk = kk - cumNext;
            }
        }
        __syncthreads();
        prefix = sh_prefix; kk = sh_kk;
        __syncthreads();
    }

    const float T = __uint_as_float(prefix);
    float sum = 0.0f; int cnt = 0;
    for (int p = tid; p < P_; p += 1024) {
        const float v = row[p];
        if (v > T) { sum += v; ++cnt; }
    }
    for (int m = 32; m; m >>= 1) {
        sum += __shfl_xor(sum, m, 64);
        cnt += __shfl_xor(cnt, m, 64);
    }
    __shared__ float wsum[16];
    __shared__ int   wcnt[16];
    if ((tid & 63) == 0) { wsum[wave] = sum; wcnt[wave] = cnt; }
    __syncthreads();
    if (tid == 0) {
        float s = 0.0f; int c2 = 0;
#pragma unroll
        for (int w = 0; w < 16; ++w) { s += wsum[w]; c2 += wcnt[w]; }
        ctop[b] = s + (float)(k - c2) * T;       // ties at threshold
    }
}

// ---------------------------------------------------------------- kernel 6
__global__ void k_final(const float* __restrict__ accs,
                        const float* __restrict__ ctop,
                        float* __restrict__ out)
{
    float c = ctop[threadIdx.x];                 // 64 threads, one per batch
    for (int m = 32; m; m >>= 1) c += __shfl_xor(c, m, 64);
    if (threadIdx.x == 0)
        out[0] = (2.0f*accs[0] + accs[1] + c) / fmaxf(accs[3], 1.0f);
}

// ----------------------------------------------------------------
extern "C" void kernel_launch(void* const* d_in, const int* in_sizes, int n_in,
                              void* d_out, int out_size, void* d_ws, size_t ws_size,
                              hipStream_t stream)
{
    const float* loc    = (const float*)d_in[0];   // [B,P,4]
    const float* conf   = (const float*)d_in[1];   // [B,P,2]
    const float* gt     = (const float*)d_in[2];   // [B,G,4]
    const int*   labels = (const int*)d_in[3];     // [B,G]
    const float* priors = (const float*)d_in[4];   // [P,4]
    float* out = (float*)d_out;

    char* ws = (char*)d_ws;
    size_t off = 0;
    float* bto = (float*)(ws + off);                 off += (size_t)B_*P_*4;  // reused as mine
    int*   bti = (int*)(ws + off);                   off += (size_t)B_*P_*4;
    unsigned long long* bp_pack =
        (unsigned long long*)(ws + off);             off += (size_t)B_*G_*8;
    float* pl = (float*)(ws + off);                  off += (size_t)NBLK_*4;
    float* pc = (float*)(ws + off);                  off += (size_t)NBLK_*4;
    int*   pp = (int*)(ws + off);                    off += (size_t)NBLK_*4;
    int*   num_pos = (int*)(ws + off);               off += (size_t)B_*4;
    float* accs = (float*)(ws + off);                off += 4*4;
    float* ctop = (float*)(ws + off);                off += (size_t)B_*4;

    hipMemsetAsync(bp_pack, 0, (size_t)B_*G_*8, stream);

    k_match<<<dim3(CH_, B_), dim3(256), 0, stream>>>(
        (const float4*)gt, (const float4*)priors, bto, bti, bp_pack);
    k_override<<<dim3(1), dim3(64), 0, stream>>>(bp_pack, bto, bti);
    k_loss<<<dim3(CH_, B_), dim3(256), 0, stream>>>(
        (const float4*)loc, (const float2*)conf, (const float4*)gt, labels,
        (const float4*)priors, bto, bti, pl, pc, pp);
    k_reduce<<<dim3(1), dim3(256), 0, stream>>>(pl, pc, pp, num_pos, accs);
    k_topk<<<dim3(B_), dim3(1024), 0, stream>>>(bto, num_pos, ctop);
    k_final<<<dim3(1), dim3(64), 0, stream>>>(accs, ctop, out);
}